// Round 9
// baseline (189.901 us; speedup 1.0000x reference)
//
#include <hip/hip_runtime.h>
#include <hip/hip_bf16.h>

typedef __bf16 bf16_t;
typedef __bf16 bf16x8 __attribute__((ext_vector_type(8)));
typedef float f32x4 __attribute__((ext_vector_type(4)));
typedef __fp16 f16x2 __attribute__((ext_vector_type(2)));

#define BATCH 4
#define SEQ 4096
#define FIN 33
#define DIM 64
#define LOG2E 1.4426950408889634f
#define NWAVE 16   // waves per WG
#define NTILE 16   // 256 cols per wave / 16 cols per MFMA tile
#define NBLK 4     // row-blocks per persistent WG

__device__ __forceinline__ float dexp2(float x) { return __builtin_amdgcn_exp2f(x); }

// ---------------- Kernel 1: q/k affine projections (fp32 math, bf16 store) ----------------
__global__ __launch_bounds__(256) void qk_proj_kernel(
    const float* __restrict__ x, const float* __restrict__ Wq,
    const float* __restrict__ bq, const float* __restrict__ Wk,
    const float* __restrict__ bk,
    bf16_t* __restrict__ qout, bf16_t* __restrict__ kout)
{
    __shared__ float sWq[FIN * DIM];
    __shared__ float sWk[FIN * DIM];
    __shared__ float sb[2 * DIM];
    const int t = threadIdx.x;
    for (int i = t; i < FIN * DIM; i += 256) { sWq[i] = Wq[i]; sWk[i] = Wk[i]; }
    if (t < DIM) { sb[t] = bq[t]; sb[DIM + t] = bk[t]; }
    __syncthreads();

    const int row = blockIdx.x * 4 + (t >> 6);   // [0, 16384)
    const int d   = t & 63;
    const float* xr = x + (size_t)row * FIN;
    float qacc = sb[d], kacc = sb[DIM + d];
#pragma unroll
    for (int f = 0; f < FIN; ++f) {
        const float xv = xr[f];
        qacc += xv * sWq[f * DIM + d];
        kacc += xv * sWk[f * DIM + d];
    }
    qout[(size_t)row * DIM + d] = (bf16_t)qacc;
    kout[(size_t)row * DIM + d] = (bf16_t)kacc;
}

// ---------------- Kernel 2: persistent fused QK^T + row-max softmax ----------------
// 256 WGs (1/CU), 1024 thr (16 waves), each WG owns 4 consecutive 16-row blocks
// of one batch. Per block: sweep->pack scores fp16 (regs), exp pass, store pass.
// The store pass of block i is fused per-tile with the sweep of block i+1
// (register handoff: store s[ct], then overwrite s[ct] with next block's tile).

__device__ __forceinline__ f32x4 mm2(bf16x8 a0, bf16x8 a1, bf16x8 b0, bf16x8 b1)
{
    f32x4 acc = {0.f, 0.f, 0.f, 0.f};
    acc = __builtin_amdgcn_mfma_f32_16x16x32_bf16(a0, b0, acc, 0, 0, 0);
    acc = __builtin_amdgcn_mfma_f32_16x16x32_bf16(a1, b1, acc, 0, 0, 0);
    return acc;
}

#define LD(ct, h) (*reinterpret_cast<const bf16x8*>(kw + (size_t)(ct) * 16 * DIM + (h) * 32))

__global__ __launch_bounds__(1024, 4) void attn_kernel(
    const bf16_t* __restrict__ qg, const bf16_t* __restrict__ kg,
    float* __restrict__ out)
{
    // XCD-contiguous swizzle: 256 WGs, XCD x gets logical wgids [x*32, x*32+32)
    // -> each XCD touches only one batch's k (2 MB fits its 4 MB L2).
    const int wgid = ((blockIdx.x & 7) << 5) | (blockIdx.x >> 3);
    const int blk0 = wgid * NBLK;      // first global row-block, 0..1023
    const int b    = blk0 >> 8;        // batch, same for all 4 blocks
    const int t    = threadIdx.x;
    const int w    = t >> 6;           // wave 0..15
    const int l    = t & 63;
    const int lr   = l & 15;           // A-row / B-col lane index
    const int kg4  = l >> 4;           // D rows kg4*4 .. +3
    const int col0 = w << 8;           // 256 cols per wave

    // k pointer: constant across all 4 blocks (same batch)
    const bf16_t* kw = kg + ((size_t)b * SEQ + col0 + lr) * DIM + kg4 * 8;

    __shared__ float redM[NWAVE][16];
    __shared__ float redZ[NWAVE][16];

    f16x2 s[NTILE][2];                 // packed scores / exp values
    float cM[4], invZ[4];

    // ---------- helpers as macros (static indexing everywhere) ----------
#define REDUCE_M(vmax)                                                          \
    {                                                                           \
        _Pragma("unroll")                                                       \
        for (int m = 1; m < 16; m <<= 1) {                                      \
            _Pragma("unroll")                                                   \
            for (int j = 0; j < 4; ++j)                                         \
                vmax[j] = fmaxf(vmax[j], __shfl_xor(vmax[j], m, 64));           \
        }                                                                       \
        if (lr == 0) {                                                          \
            _Pragma("unroll")                                                   \
            for (int j = 0; j < 4; ++j) redM[w][kg4 * 4 + j] = vmax[j];         \
        }                                                                       \
        __syncthreads();                                                        \
        _Pragma("unroll")                                                       \
        for (int j = 0; j < 4; ++j) {                                           \
            const int r = kg4 * 4 + j;                                          \
            float mm = redM[0][r];                                              \
            _Pragma("unroll")                                                   \
            for (int ww = 1; ww < NWAVE; ++ww) mm = fmaxf(mm, redM[ww][r]);     \
            cM[j] = LOG2E / mm;                                                 \
        }                                                                       \
    }

#define PASS_B()                                                                \
    {                                                                           \
        float vsum[4] = {0.f, 0.f, 0.f, 0.f};                                   \
        _Pragma("unroll")                                                       \
        for (int ct = 0; ct < NTILE; ++ct) {                                    \
            _Pragma("unroll")                                                   \
            for (int h = 0; h < 2; ++h) {                                       \
                const float e0 = dexp2(fmaf((float)s[ct][h][0], cM[2*h+0], -LOG2E)); \
                const float e1 = dexp2(fmaf((float)s[ct][h][1], cM[2*h+1], -LOG2E)); \
                vsum[2*h+0] += e0;                                              \
                vsum[2*h+1] += e1;                                              \
                s[ct][h] = __builtin_amdgcn_cvt_pkrtz(e0, e1);                  \
            }                                                                   \
        }                                                                       \
        _Pragma("unroll")                                                       \
        for (int m = 1; m < 16; m <<= 1) {                                      \
            _Pragma("unroll")                                                   \
            for (int j = 0; j < 4; ++j) vsum[j] += __shfl_xor(vsum[j], m, 64);  \
        }                                                                       \
        if (lr == 0) {                                                          \
            _Pragma("unroll")                                                   \
            for (int j = 0; j < 4; ++j) redZ[w][kg4 * 4 + j] = vsum[j];         \
        }                                                                       \
        __syncthreads();                                                        \
        _Pragma("unroll")                                                       \
        for (int j = 0; j < 4; ++j) {                                           \
            const int r = kg4 * 4 + j;                                          \
            float z = redZ[0][r];                                               \
            _Pragma("unroll")                                                   \
            for (int ww = 1; ww < NWAVE; ++ww) z += redZ[ww][r];                \
            invZ[j] = 1.0f / z;                                                 \
        }                                                                       \
    }

    // ---------- prologue: pass A for block 0 ----------
    {
        const bf16_t* qb = qg + (size_t)(blk0 * 16) * DIM;
        const bf16x8 a0 = *reinterpret_cast<const bf16x8*>(qb + lr * DIM + kg4 * 8);
        const bf16x8 a1 = *reinterpret_cast<const bf16x8*>(qb + lr * DIM + 32 + kg4 * 8);
        float vmax[4] = {-3.4e38f, -3.4e38f, -3.4e38f, -3.4e38f};
        bf16x8 p0a = LD(0, 0), p0b = LD(0, 1);
        bf16x8 p1a = LD(1, 0), p1b = LD(1, 1);
#pragma unroll
        for (int ct = 0; ct < NTILE; ct += 2) {
            f32x4 acc0 = mm2(a0, a1, p0a, p0b);
            if (ct + 2 < NTILE) { p0a = LD(ct + 2, 0); p0b = LD(ct + 2, 1); }
#pragma unroll
            for (int j = 0; j < 4; ++j) vmax[j] = fmaxf(vmax[j], acc0[j]);
            s[ct][0] = __builtin_amdgcn_cvt_pkrtz(acc0[0], acc0[1]);
            s[ct][1] = __builtin_amdgcn_cvt_pkrtz(acc0[2], acc0[3]);

            f32x4 acc1 = mm2(a0, a1, p1a, p1b);
            if (ct + 3 < NTILE) { p1a = LD(ct + 3, 0); p1b = LD(ct + 3, 1); }
#pragma unroll
            for (int j = 0; j < 4; ++j) vmax[j] = fmaxf(vmax[j], acc1[j]);
            s[ct + 1][0] = __builtin_amdgcn_cvt_pkrtz(acc1[0], acc1[1]);
            s[ct + 1][1] = __builtin_amdgcn_cvt_pkrtz(acc1[2], acc1[3]);
        }
        REDUCE_M(vmax);
        PASS_B();
    }

    // ---------- main loop: store block i fused with sweep of block i+1 ----------
#pragma unroll
    for (int i = 0; i < NBLK; ++i) {
        const int blk = blk0 + i;
        float* orow = out + ((size_t)(blk * 16 + kg4 * 4)) * SEQ + col0 + lr;
        if (i + 1 < NBLK) {
            const bf16_t* qb = qg + (size_t)((blk + 1) * 16) * DIM;
            const bf16x8 a0 = *reinterpret_cast<const bf16x8*>(qb + lr * DIM + kg4 * 8);
            const bf16x8 a1 = *reinterpret_cast<const bf16x8*>(qb + lr * DIM + 32 + kg4 * 8);
            float vmax[4] = {-3.4e38f, -3.4e38f, -3.4e38f, -3.4e38f};
            bf16x8 p0a = LD(0, 0), p0b = LD(0, 1);
            bf16x8 p1a = LD(1, 0), p1b = LD(1, 1);
#pragma unroll
            for (int ct = 0; ct < NTILE; ct += 2) {
                // tile ct: compute next block, then store old, then overwrite s[ct]
                f32x4 acc0 = mm2(a0, a1, p0a, p0b);
                if (ct + 2 < NTILE) { p0a = LD(ct + 2, 0); p0b = LD(ct + 2, 1); }
                orow[(size_t)0 * SEQ + ct * 16] = (float)s[ct][0][0] * invZ[0];
                orow[(size_t)1 * SEQ + ct * 16] = (float)s[ct][0][1] * invZ[1];
                orow[(size_t)2 * SEQ + ct * 16] = (float)s[ct][1][0] * invZ[2];
                orow[(size_t)3 * SEQ + ct * 16] = (float)s[ct][1][1] * invZ[3];
#pragma unroll
                for (int j = 0; j < 4; ++j) vmax[j] = fmaxf(vmax[j], acc0[j]);
                s[ct][0] = __builtin_amdgcn_cvt_pkrtz(acc0[0], acc0[1]);
                s[ct][1] = __builtin_amdgcn_cvt_pkrtz(acc0[2], acc0[3]);

                // tile ct+1
                f32x4 acc1 = mm2(a0, a1, p1a, p1b);
                if (ct + 3 < NTILE) { p1a = LD(ct + 3, 0); p1b = LD(ct + 3, 1); }
                orow[(size_t)0 * SEQ + (ct + 1) * 16] = (float)s[ct + 1][0][0] * invZ[0];
                orow[(size_t)1 * SEQ + (ct + 1) * 16] = (float)s[ct + 1][0][1] * invZ[1];
                orow[(size_t)2 * SEQ + (ct + 1) * 16] = (float)s[ct + 1][1][0] * invZ[2];
                orow[(size_t)3 * SEQ + (ct + 1) * 16] = (float)s[ct + 1][1][1] * invZ[3];
#pragma unroll
                for (int j = 0; j < 4; ++j) vmax[j] = fmaxf(vmax[j], acc1[j]);
                s[ct + 1][0] = __builtin_amdgcn_cvt_pkrtz(acc1[0], acc1[1]);
                s[ct + 1][1] = __builtin_amdgcn_cvt_pkrtz(acc1[2], acc1[3]);
            }
            REDUCE_M(vmax);
            PASS_B();
        } else {
            // epilogue: plain store pass for the last block
#pragma unroll
            for (int ct = 0; ct < NTILE; ++ct) {
                orow[(size_t)0 * SEQ + ct * 16] = (float)s[ct][0][0] * invZ[0];
                orow[(size_t)1 * SEQ + ct * 16] = (float)s[ct][0][1] * invZ[1];
                orow[(size_t)2 * SEQ + ct * 16] = (float)s[ct][1][0] * invZ[2];
                orow[(size_t)3 * SEQ + ct * 16] = (float)s[ct][1][1] * invZ[3];
            }
        }
    }
}

extern "C" void kernel_launch(void* const* d_in, const int* in_sizes, int n_in,
                              void* d_out, int out_size, void* d_ws, size_t ws_size,
                              hipStream_t stream)
{
    const float* x  = (const float*)d_in[0];
    const float* Wq = (const float*)d_in[1];
    const float* bq = (const float*)d_in[2];
    const float* Wk = (const float*)d_in[3];
    const float* bk = (const float*)d_in[4];
    float* out = (float*)d_out;

    bf16_t* qws = (bf16_t*)d_ws;
    bf16_t* kws = qws + (size_t)BATCH * SEQ * DIM;

    qk_proj_kernel<<<(BATCH * SEQ) / 4, 256, 0, stream>>>(x, Wq, bq, Wk, bk, qws, kws);
    attn_kernel<<<256, 1024, 0, stream>>>(qws, kws, out);
}